// Round 6
// baseline (38.327 us; speedup 1.0000x reference)
//
#include <hip/hip_runtime.h>
#include <hip/hip_bf16.h>

// R17 = R16 + 2x LDS-read reuse (theory: R16 is LDS-BW-bound).
// Accounting: each R16 wave read full K (8KB) + V (8KB) tiles per tile for
// only 16 q-rows; 16 waves/CU -> ~288KB LDS traffic per CU-tile ~ 2250 clk
// at 128B/clk, matching the observed ~2350-cyc tile period. MFMA (360
// cyc/SIMD) and VALU (~640) sit far below. Fix = operand reuse:
// - 256-thread blocks (4 waves); each wave owns 32 q-rows as TWO 16-row
//   fragments (f=0,1). Every kb/vb fragment ds_read now feeds 2 MFMAs.
//   K/V LDS reads per CU-tile halve: 288KB -> 160KB (~1250 clk floor).
// - Same QT=128, grid 512, 2 blocks/CU (8 waves/CU, 2/SIMD). LDS 32896 B.
// - Staging: R11's verified full 256-thread mapping (K part with R16's prow
//   permutation, V part swz8) -- same tile images as R16.
// - Softmax/mask/defer-max duplicated per fragment; skip-vote stays at
//   16-row granularity (same grouping as R16's waves) -> bit-identical output.
// - max reduce as explicit tree (depth 4, v_max3-fusable) instead of a
//   16-deep serial fmax chain.

#define NB    64
#define LQ    1024
#define LK    1024
#define DH    64
#define KVT   64
#define QT    128
#define NITEMS (NB * (LQ / QT))      // 512
#define NEGF  1.0e30f
#define SC2   0.18033688011112042f   // 0.125 * log2(e)
#define THR   8.0f                   // defer-max threshold (log2 units)

typedef __attribute__((ext_vector_type(8))) short    bf8;
typedef __attribute__((ext_vector_type(8))) ushort   u16x8;
typedef __attribute__((ext_vector_type(4))) ushort   u16x4;
typedef __attribute__((ext_vector_type(4))) float    f4;

__device__ __forceinline__ ushort2 cvt2(float a, float b) {   // v_cvt_pk_bf16_f32
    float2 f; f.x = a; f.y = b;
    __hip_bfloat162 h = __float22bfloat162_rn(f);
    union { __hip_bfloat162 h2; ushort2 u2; } u;
    u.h2 = h;
    return u.u2;
}
__device__ __forceinline__ int swz16(int row, int colbyte) {  // K tile
    return row * 128 + ((((colbyte >> 4) ^ (row & 7)) << 4) | (colbyte & 15));
}
__device__ __forceinline__ int swz8(int row, int colbyte) {   // V^T tile
    return row * 128 + ((((colbyte >> 3) ^ (row & 15)) << 3) | (colbyte & 7));
}

__global__ __launch_bounds__(256, 2)
void attn_v17(const float* __restrict__ Q, const float* __restrict__ K,
              const float* __restrict__ V, const int* __restrict__ VL,
              float* __restrict__ O) {
    __shared__ ushort KsB[2][KVT * DH];   // swz16 [phys key][d] 16 KB
    __shared__ ushort VtB[2][DH * KVT];   // swz8  [d][key]      16 KB
    __shared__ ushort sched[NB];          // rank -> batch        128 B => 32896

    const int tid = threadIdx.x;
    const int wid = tid >> 6, l = tid & 63, g = l >> 4, a = l & 15;

    // ---- in-kernel stratified-LPT schedule ----
    if (tid < NB) {
        const int ntb = (VL[tid] + KVT - 1) >> 6;
        int r = 0;
        for (int j = 0; j < NB; ++j) {
            const int ntj = (VL[j] + KVT - 1) >> 6;
            r += (int)((ntj > ntb) | ((ntj == ntb) & (j < tid)));
        }
        sched[r] = (ushort)tid;           // rank -> batch (desc nt, tie asc)
    }
    __syncthreads();
    const int xcd   = blockIdx.x & 7;     // HW: block i -> XCD i%8
    const int slot  = blockIdx.x >> 3;    // 0..63 within XCD
    const int qtile = slot & 7;           // 8 q-slots of 128 rows
    const int st    = slot >> 3;          // stratum 0..7
    // pairing perm8={0,1,2,3,7,6,5,4}: CU gets complementary strata
    const int rank  = xcd + ((st < 4) ? st : (11 - st)) * 8;
    const int b     = sched[rank];
    const int qbase = qtile * QT;
    const int valid = VL[b];              // 1..1024
    const int nt = (valid + KVT - 1) >> 6;

    // Q fragments (B-operand), pre-scaled by SC2: fragment f covers q-rows
    // qbase + wid*32 + f*16 + a; k = 32kblk + 8g + i
    bf8 qa[2][2];
    #pragma unroll
    for (int f = 0; f < 2; ++f) {
        const float* Qr = Q + ((size_t)b * LQ + qbase + wid * 32 + f * 16 + a) * DH;
        #pragma unroll
        for (int kblk = 0; kblk < 2; ++kblk) {
            f4 x = *(const f4*)(Qr + kblk * 32 + g * 8);
            f4 y = *(const f4*)(Qr + kblk * 32 + g * 8 + 4);
            ushort2 c0 = cvt2(x[0] * SC2, x[1] * SC2), c1 = cvt2(x[2] * SC2, x[3] * SC2);
            ushort2 c2 = cvt2(y[0] * SC2, y[1] * SC2), c3 = cvt2(y[2] * SC2, y[3] * SC2);
            qa[f][kblk][0] = (short)c0.x; qa[f][kblk][1] = (short)c0.y;
            qa[f][kblk][2] = (short)c1.x; qa[f][kblk][3] = (short)c1.y;
            qa[f][kblk][4] = (short)c2.x; qa[f][kblk][5] = (short)c2.y;
            qa[f][kblk][6] = (short)c3.x; qa[f][kblk][7] = (short)c3.y;
        }
    }
    const bf8 ones = {0x3F80, 0x3F80, 0x3F80, 0x3F80,
                      0x3F80, 0x3F80, 0x3F80, 0x3F80};   // bf16 1.0 x8

    // staging: R11's full 256-thread mapping (verified), K rows permuted
    const int srow = tid >> 3, sslot = tid & 7;   // K rows srow, srow+32
    const int vkp  = tid >> 4, vj = tid & 15;     // V keys 4vkp.., f4-col vj
    // physical LDS row for K key srow (<32): swap bits 3..4 with bit 2
    const int prow = (srow & 3) | ((srow & 24) >> 1) | ((srow & 4) << 2);
    const f4* Kb4 = (const f4*)(K + (size_t)b * LK * DH);
    const f4* Vb4 = (const f4*)(V + (size_t)b * LK * DH);

    f4 kr0, kr1, kr2, kr3, vr0, vr1, vr2, vr3;
    auto load_kv = [&](int k0) {
        kr0 = Kb4[(k0 + srow) * 16 + sslot * 2];
        kr1 = Kb4[(k0 + srow) * 16 + sslot * 2 + 1];
        kr2 = Kb4[(k0 + srow + 32) * 16 + sslot * 2];
        kr3 = Kb4[(k0 + srow + 32) * 16 + sslot * 2 + 1];
        vr0 = Vb4[(k0 + 4 * vkp + 0) * 16 + vj];
        vr1 = Vb4[(k0 + 4 * vkp + 1) * 16 + vj];
        vr2 = Vb4[(k0 + 4 * vkp + 2) * 16 + vj];
        vr3 = Vb4[(k0 + 4 * vkp + 3) * 16 + vj];
    };
    auto store_kv = [&](int bs) {
        char* kd = (char*)&KsB[bs][0];
        {
            ushort2 c0 = cvt2(kr0[0], kr0[1]), c1 = cvt2(kr0[2], kr0[3]);
            ushort2 c2 = cvt2(kr1[0], kr1[1]), c3 = cvt2(kr1[2], kr1[3]);
            u16x8 w = {c0.x, c0.y, c1.x, c1.y, c2.x, c2.y, c3.x, c3.y};
            *(u16x8*)(kd + swz16(prow, sslot * 16)) = w;
        }
        {
            ushort2 c0 = cvt2(kr2[0], kr2[1]), c1 = cvt2(kr2[2], kr2[3]);
            ushort2 c2 = cvt2(kr3[0], kr3[1]), c3 = cvt2(kr3[2], kr3[3]);
            u16x8 w = {c0.x, c0.y, c1.x, c1.y, c2.x, c2.y, c3.x, c3.y};
            *(u16x8*)(kd + swz16(prow + 32, sslot * 16)) = w;
        }
        char* vd = (char*)&VtB[bs][0];
        #pragma unroll
        for (int c = 0; c < 4; ++c) {          // transpose: d = 4*vj+c
            ushort2 a01 = cvt2(vr0[c], vr1[c]), a23 = cvt2(vr2[c], vr3[c]);
            u16x4 p = {a01.x, a01.y, a23.x, a23.y};
            *(u16x4*)(vd + swz8(4 * vj + c, vkp * 8)) = p;
        }
    };

    f4 oacc[2][4];
    #pragma unroll
    for (int f = 0; f < 2; ++f)
        #pragma unroll
        for (int n = 0; n < 4; ++n) oacc[f][n] = f4{0.f, 0.f, 0.f, 0.f};
    f4 lacc[2] = {f4{0.f, 0.f, 0.f, 0.f}, f4{0.f, 0.f, 0.f, 0.f}};
    float m_run[2] = {-NEGF, -NEGF};    // per-lane: q-row = a (per fragment)

    load_kv(0);
    store_kv(0);
    for (int t = 0; t < nt; ++t) {
        const int bs = t & 1;
        __syncthreads();                         // buf[bs] ready block-wide
        if (t + 1 < nt) load_kv((t + 1) * KVT);  // issue early...
        __builtin_amdgcn_sched_barrier(0);       // ...keep it early

        // ---- S^T = K Q^T: phys rows n*16+a => lane (g,a), fragment f, holds
        //      S[q][key = 32*(n>>1) + 4*(n&1) + 8g + r] ----
        const char* kd = (const char*)&KsB[bs][0];
        f4 sacc[2][4];
        #pragma unroll
        for (int f = 0; f < 2; ++f)
            #pragma unroll
            for (int n = 0; n < 4; ++n) sacc[f][n] = f4{0.f, 0.f, 0.f, 0.f};
        __builtin_amdgcn_s_setprio(1);
        #pragma unroll
        for (int n = 0; n < 4; ++n)
            #pragma unroll
            for (int kblk = 0; kblk < 2; ++kblk) {
                bf8 kb = *(const bf8*)(kd + swz16(n * 16 + a, kblk * 64 + g * 16));
                sacc[0][n] = __builtin_amdgcn_mfma_f32_16x16x32_bf16(
                    kb, qa[0][kblk], sacc[0][n], 0, 0, 0);   // A=K, B=Q(f0)
                sacc[1][n] = __builtin_amdgcn_mfma_f32_16x16x32_bf16(
                    kb, qa[1][kblk], sacc[1][n], 0, 0, 0);   // reuse kb (f1)
            }
        __builtin_amdgcn_s_setprio(0);

        float p[2][4][4];
        const int kmax = valid - t * KVT;
        #pragma unroll
        for (int f = 0; f < 2; ++f) {
            float s[4][4];
            #pragma unroll
            for (int n = 0; n < 4; ++n)
                #pragma unroll
                for (int r = 0; r < 4; ++r) s[n][r] = sacc[f][n][r];
            if (kmax < KVT) {
                #pragma unroll
                for (int n = 0; n < 4; ++n)
                    #pragma unroll
                    for (int r = 0; r < 4; ++r)
                        if (32 * (n >> 1) + 4 * (n & 1) + 8 * g + r >= kmax)
                            s[n][r] = -NEGF;
            }

            // max: explicit tree (depth 4) + 2 shfl over g
            float m0 = fmaxf(fmaxf(s[0][0], s[0][1]), fmaxf(s[0][2], s[0][3]));
            float m1 = fmaxf(fmaxf(s[1][0], s[1][1]), fmaxf(s[1][2], s[1][3]));
            float m2 = fmaxf(fmaxf(s[2][0], s[2][1]), fmaxf(s[2][2], s[2][3]));
            float m3 = fmaxf(fmaxf(s[3][0], s[3][1]), fmaxf(s[3][2], s[3][3]));
            float tm = fmaxf(fmaxf(m0, m1), fmaxf(m2, m3));
            tm = fmaxf(tm, __shfl_xor(tm, 16));
            tm = fmaxf(tm, __shfl_xor(tm, 32));

            float rs_ = 1.0f;                     // T13 defer-max
            const bool skip = __all(tm <= m_run[f] + THR);
            if (!skip) {
                const float mnew = fmaxf(m_run[f], tm);
                rs_ = __builtin_exp2f(m_run[f] - mnew);   // tile0: exp2(-inf)=0
                m_run[f] = mnew;
            }

            #pragma unroll
            for (int n = 0; n < 4; ++n)
                #pragma unroll
                for (int r = 0; r < 4; ++r)
                    p[f][n][r] = __builtin_exp2f(s[n][r] - m_run[f]);  // masked->0

            if (!skip) {   // rescale O,l rows (q=4g+r)
                float rr[4];
                #pragma unroll
                for (int r = 0; r < 4; ++r) rr[r] = __shfl(rs_, 4 * g + r);
                #pragma unroll
                for (int n = 0; n < 4; ++n)
                    #pragma unroll
                    for (int r = 0; r < 4; ++r) oacc[f][n][r] *= rr[r];
                #pragma unroll
                for (int r = 0; r < 4; ++r) lacc[f][r] *= rr[r];
            }
        }

        // ---- O += P V ; l += P * ones  (P in registers; vb reused 2x) ----
        const char* vd = (const char*)&VtB[bs][0];
        __builtin_amdgcn_s_setprio(1);
        #pragma unroll
        for (int kblk = 0; kblk < 2; ++kblk) {
            bf8 pa[2];
            #pragma unroll
            for (int f = 0; f < 2; ++f) {
                ushort2 w0 = cvt2(p[f][2 * kblk][0], p[f][2 * kblk][1]);
                ushort2 w1 = cvt2(p[f][2 * kblk][2], p[f][2 * kblk][3]);
                ushort2 w2 = cvt2(p[f][2 * kblk + 1][0], p[f][2 * kblk + 1][1]);
                ushort2 w3 = cvt2(p[f][2 * kblk + 1][2], p[f][2 * kblk + 1][3]);
                pa[f][0] = (short)w0.x; pa[f][1] = (short)w0.y;
                pa[f][2] = (short)w1.x; pa[f][3] = (short)w1.y;
                pa[f][4] = (short)w2.x; pa[f][5] = (short)w2.y;
                pa[f][6] = (short)w3.x; pa[f][7] = (short)w3.y;
            }
            const int cb = kblk * 64 + g * 16;
            #pragma unroll
            for (int n = 0; n < 4; ++n) {
                u16x4 lo = *(const u16x4*)(vd + swz8(n * 16 + a, cb));
                u16x4 hi = *(const u16x4*)(vd + swz8(n * 16 + a, cb + 8));
                bf8 vb_ = {(short)lo[0], (short)lo[1], (short)lo[2], (short)lo[3],
                           (short)hi[0], (short)hi[1], (short)hi[2], (short)hi[3]};
                oacc[0][n] = __builtin_amdgcn_mfma_f32_16x16x32_bf16(
                    pa[0], vb_, oacc[0][n], 0, 0, 0);
                oacc[1][n] = __builtin_amdgcn_mfma_f32_16x16x32_bf16(
                    pa[1], vb_, oacc[1][n], 0, 0, 0);      // reuse vb_
            }
            lacc[0] = __builtin_amdgcn_mfma_f32_16x16x32_bf16(pa[0], ones, lacc[0], 0, 0, 0);
            lacc[1] = __builtin_amdgcn_mfma_f32_16x16x32_bf16(pa[1], ones, lacc[1], 0, 0, 0);
        }
        __builtin_amdgcn_s_setprio(0);

        if (t + 1 < nt) store_kv(bs ^ 1);   // post-compute, pre-next-barrier
    }

    // ---- epilogue: per fragment, O[q=4g+r][d=16n+a] / l ----
    #pragma unroll
    for (int f = 0; f < 2; ++f) {
        float iv[4];
        #pragma unroll
        for (int r = 0; r < 4; ++r) iv[r] = 1.0f / lacc[f][r];
        float* Ob = O + ((size_t)b * LQ + qbase + wid * 32 + f * 16) * DH;
        #pragma unroll
        for (int n = 0; n < 4; ++n)
            #pragma unroll
            for (int r = 0; r < 4; ++r)
                Ob[(size_t)(4 * g + r) * DH + 16 * n + a] = oacc[f][n][r] * iv[r];
    }
}

extern "C" void kernel_launch(void* const* d_in, const int* in_sizes, int n_in,
                              void* d_out, int out_size, void* d_ws, size_t ws_size,
                              hipStream_t stream) {
    const float* Q  = (const float*)d_in[0];
    const float* K  = (const float*)d_in[1];
    const float* V  = (const float*)d_in[2];
    const int*   VL = (const int*)d_in[3];
    float* O = (float*)d_out;

    attn_v17<<<NITEMS, 256, 0, stream>>>(Q, K, V, VL, O);
}

// Round 7
// 38.321 us; speedup vs baseline: 1.0002x; 1.0002x over previous
//
#include <hip/hip_runtime.h>
#include <hip/hip_bf16.h>

// R18 = R16 (verified 33.6us) + two-phase pipelined K-loop.
// R17 post-mortem: halving LDS reads REGRESSED (38.3us, Occ 13%, VALUBusy 33%)
// -> kernel is LATENCY-bound, not LDS-BW-bound; TLP (4 waves/SIMD) is load-
// bearing. So keep R16's shape (512 thr, 8 waves x 16 q-rows, QT=128, grid
// 512, in-register P via prow-permuted K) and shorten/overlap the chain:
//   iter t:  sec1 { softmax(t)->pa regs ; store_kv(t+1) }   (pure VALU/DS-write)
//            B1
//            sec2 { load_kv(t+2); QK(t+1) || PV(t) }        (MFMA + ds_read)
//            B2
// - QK(t+1) no longer waits behind softmax(t): two independent MFMA streams
//   per wave in sec2; sec1/sec2 role-split lets the 2 blocks/CU overlap
//   complementarily (VALU block || MFMA block).
// - Buffer lifetimes: B2 protects {K,V}[bs] (sec2 reads, iter t) from
//   store_kv(bs) (sec1, iter t+1); B1 protects K[bs^1] from its own staging.
//   Single sacc/pa register set: consumed in sec1, refilled in sec2 (static).
// - Tree-structured 16-value max (depth 4) from R17 kept (v_max3-fusable).
// Arithmetic order identical to R16 -> output bit-identical.

#define NB    64
#define LQ    1024
#define LK    1024
#define DH    64
#define KVT   64
#define QT    128
#define NITEMS (NB * (LQ / QT))      // 512
#define NEGF  1.0e30f
#define SC2   0.18033688011112042f   // 0.125 * log2(e)
#define THR   8.0f                   // defer-max threshold (log2 units)

typedef __attribute__((ext_vector_type(8))) short    bf8;
typedef __attribute__((ext_vector_type(8))) ushort   u16x8;
typedef __attribute__((ext_vector_type(4))) ushort   u16x4;
typedef __attribute__((ext_vector_type(4))) float    f4;

__device__ __forceinline__ ushort2 cvt2(float a, float b) {   // v_cvt_pk_bf16_f32
    float2 f; f.x = a; f.y = b;
    __hip_bfloat162 h = __float22bfloat162_rn(f);
    union { __hip_bfloat162 h2; ushort2 u2; } u;
    u.h2 = h;
    return u.u2;
}
__device__ __forceinline__ int swz16(int row, int colbyte) {  // K tile
    return row * 128 + ((((colbyte >> 4) ^ (row & 7)) << 4) | (colbyte & 15));
}
__device__ __forceinline__ int swz8(int row, int colbyte) {   // V^T tile
    return row * 128 + ((((colbyte >> 3) ^ (row & 15)) << 3) | (colbyte & 7));
}

__global__ __launch_bounds__(512, 4)
void attn_v18(const float* __restrict__ Q, const float* __restrict__ K,
              const float* __restrict__ V, const int* __restrict__ VL,
              float* __restrict__ O) {
    __shared__ ushort KsB[2][KVT * DH];   // swz16 [phys key][d] 16 KB
    __shared__ ushort VtB[2][DH * KVT];   // swz8  [d][key]      16 KB
    __shared__ ushort sched[NB];          // rank -> batch        128 B => 32896

    const int tid = threadIdx.x;
    const int wid = tid >> 6, l = tid & 63, g = l >> 4, a = l & 15;

    // ---- in-kernel stratified-LPT schedule ----
    if (tid < NB) {
        const int ntb = (VL[tid] + KVT - 1) >> 6;
        int r = 0;
        for (int j = 0; j < NB; ++j) {
            const int ntj = (VL[j] + KVT - 1) >> 6;
            r += (int)((ntj > ntb) | ((ntj == ntb) & (j < tid)));
        }
        sched[r] = (ushort)tid;           // rank -> batch (desc nt, tie asc)
    }
    __syncthreads();
    const int xcd   = blockIdx.x & 7;     // HW: block i -> XCD i%8
    const int slot  = blockIdx.x >> 3;    // 0..63 within XCD
    const int qtile = slot & 7;           // 8 q-slots of 128 rows
    const int st    = slot >> 3;          // stratum 0..7
    // pairing perm8={0,1,2,3,7,6,5,4}: CU gets complementary strata
    const int rank  = xcd + ((st < 4) ? st : (11 - st)) * 8;
    const int b     = sched[rank];
    const int qbase = qtile * QT;
    const int valid = VL[b];              // 1..1024
    const int nt = (valid + KVT - 1) >> 6;

    // Q fragment (B-operand), pre-scaled by SC2: col=a (q-row), k=32kblk+8g+i
    const float* Qr = Q + ((size_t)b * LQ + qbase + wid * 16 + a) * DH;
    bf8 qa[2];
    #pragma unroll
    for (int kblk = 0; kblk < 2; ++kblk) {
        f4 x = *(const f4*)(Qr + kblk * 32 + g * 8);
        f4 y = *(const f4*)(Qr + kblk * 32 + g * 8 + 4);
        ushort2 c0 = cvt2(x[0] * SC2, x[1] * SC2), c1 = cvt2(x[2] * SC2, x[3] * SC2);
        ushort2 c2 = cvt2(y[0] * SC2, y[1] * SC2), c3 = cvt2(y[2] * SC2, y[3] * SC2);
        qa[kblk][0] = (short)c0.x; qa[kblk][1] = (short)c0.y;
        qa[kblk][2] = (short)c1.x; qa[kblk][3] = (short)c1.y;
        qa[kblk][4] = (short)c2.x; qa[kblk][5] = (short)c2.y;
        qa[kblk][6] = (short)c3.x; qa[kblk][7] = (short)c3.y;
    }
    const bf8 ones = {0x3F80, 0x3F80, 0x3F80, 0x3F80,
                      0x3F80, 0x3F80, 0x3F80, 0x3F80};   // bf16 1.0 x8

    // staging roles: waves 0-3 stage V, waves 4-7 stage K (R16 split)
    const int  rtid  = tid & 255;
    const bool vrole = (wid < 4);
    const int srow = rtid >> 3, sslot = rtid & 7;   // K rows srow, srow+32
    const int vkp  = rtid >> 4, vj = rtid & 15;     // V keys 4vkp.., f4-col vj
    // physical LDS row for K key srow (<32): swap bits 3..4 with bit 2
    const int prow = (srow & 3) | ((srow & 24) >> 1) | ((srow & 4) << 2);
    const f4* Kb4 = (const f4*)(K + (size_t)b * LK * DH);
    const f4* Vb4 = (const f4*)(V + (size_t)b * LK * DH);

    f4 r0, r1, r2, r3;
    auto load_kv = [&](int k0) {
        if (vrole) {
            r0 = Vb4[(k0 + 4 * vkp + 0) * 16 + vj];
            r1 = Vb4[(k0 + 4 * vkp + 1) * 16 + vj];
            r2 = Vb4[(k0 + 4 * vkp + 2) * 16 + vj];
            r3 = Vb4[(k0 + 4 * vkp + 3) * 16 + vj];
        } else {
            r0 = Kb4[(k0 + srow) * 16 + sslot * 2];
            r1 = Kb4[(k0 + srow) * 16 + sslot * 2 + 1];
            r2 = Kb4[(k0 + srow + 32) * 16 + sslot * 2];
            r3 = Kb4[(k0 + srow + 32) * 16 + sslot * 2 + 1];
        }
    };
    auto store_kv = [&](int bs) {
        if (vrole) {
            char* vd = (char*)&VtB[bs][0];
            #pragma unroll
            for (int c = 0; c < 4; ++c) {      // transpose: d = 4*vj+c
                ushort2 a01 = cvt2(r0[c], r1[c]), a23 = cvt2(r2[c], r3[c]);
                u16x4 p = {a01.x, a01.y, a23.x, a23.y};
                *(u16x4*)(vd + swz8(4 * vj + c, vkp * 8)) = p;
            }
        } else {
            char* kd = (char*)&KsB[bs][0];
            {
                ushort2 c0 = cvt2(r0[0], r0[1]), c1 = cvt2(r0[2], r0[3]);
                ushort2 c2 = cvt2(r1[0], r1[1]), c3 = cvt2(r1[2], r1[3]);
                u16x8 w = {c0.x, c0.y, c1.x, c1.y, c2.x, c2.y, c3.x, c3.y};
                *(u16x8*)(kd + swz16(prow, sslot * 16)) = w;
            }
            {
                ushort2 c0 = cvt2(r2[0], r2[1]), c1 = cvt2(r2[2], r2[3]);
                ushort2 c2 = cvt2(r3[0], r3[1]), c3 = cvt2(r3[2], r3[3]);
                u16x8 w = {c0.x, c0.y, c1.x, c1.y, c2.x, c2.y, c3.x, c3.y};
                *(u16x8*)(kd + swz16(prow + 32, sslot * 16)) = w;
            }
        }
    };

    f4 sacc[4];
    auto do_qk = [&](int bufK) {   // sacc = K[bufK] . Q^T  (refills sacc)
        const char* kd = (const char*)&KsB[bufK][0];
        #pragma unroll
        for (int n = 0; n < 4; ++n) sacc[n] = f4{0.f, 0.f, 0.f, 0.f};
        #pragma unroll
        for (int n = 0; n < 4; ++n)
            #pragma unroll
            for (int kblk = 0; kblk < 2; ++kblk) {
                bf8 kb = *(const bf8*)(kd + swz16(n * 16 + a, kblk * 64 + g * 16));
                sacc[n] = __builtin_amdgcn_mfma_f32_16x16x32_bf16(
                    kb, qa[kblk], sacc[n], 0, 0, 0);   // A=K, B=Q
            }
    };

    f4 oacc[4];
    #pragma unroll
    for (int n = 0; n < 4; ++n) oacc[n] = f4{0.f, 0.f, 0.f, 0.f};
    f4 lacc = f4{0.f, 0.f, 0.f, 0.f};   // l per q-row 4g+r (epilogue layout)
    float m_run = -NEGF;                // per-lane: q-row = a

    // ---- prologue: stage tile0, QK(0), issue tile1 loads ----
    load_kv(0);
    store_kv(0);
    __syncthreads();
    __builtin_amdgcn_s_setprio(1);
    do_qk(0);
    __builtin_amdgcn_s_setprio(0);
    if (nt > 1) load_kv(KVT);

    for (int t = 0; t < nt; ++t) {
        const int bs = t & 1;
        // ================= sec1: softmax(t) -> pa ; stage t+1 =============
        float s[4][4];
        const int kmax = valid - t * KVT;
        #pragma unroll
        for (int n = 0; n < 4; ++n)
            #pragma unroll
            for (int r = 0; r < 4; ++r) s[n][r] = sacc[n][r];
        if (kmax < KVT) {
            #pragma unroll
            for (int n = 0; n < 4; ++n)
                #pragma unroll
                for (int r = 0; r < 4; ++r)
                    if (32 * (n >> 1) + 4 * (n & 1) + 8 * g + r >= kmax)
                        s[n][r] = -NEGF;
        }

        // max: explicit tree (depth 4) + 2 shfl over g
        float m0 = fmaxf(fmaxf(s[0][0], s[0][1]), fmaxf(s[0][2], s[0][3]));
        float m1 = fmaxf(fmaxf(s[1][0], s[1][1]), fmaxf(s[1][2], s[1][3]));
        float m2 = fmaxf(fmaxf(s[2][0], s[2][1]), fmaxf(s[2][2], s[2][3]));
        float m3 = fmaxf(fmaxf(s[3][0], s[3][1]), fmaxf(s[3][2], s[3][3]));
        float tm = fmaxf(fmaxf(m0, m1), fmaxf(m2, m3));
        tm = fmaxf(tm, __shfl_xor(tm, 16));
        tm = fmaxf(tm, __shfl_xor(tm, 32));

        float rs_ = 1.0f;                     // T13 defer-max
        const bool skip = __all(tm <= m_run + THR);
        if (!skip) {
            const float mnew = fmaxf(m_run, tm);
            rs_ = __builtin_exp2f(m_run - mnew);   // tile0: exp2(-inf)=0
            m_run = mnew;
        }

        float p[4][4];
        #pragma unroll
        for (int n = 0; n < 4; ++n)
            #pragma unroll
            for (int r = 0; r < 4; ++r)
                p[n][r] = __builtin_exp2f(s[n][r] - m_run);   // masked -> 0

        if (!skip) {   // rescale O,l rows (q=4g+r)
            float rr[4];
            #pragma unroll
            for (int r = 0; r < 4; ++r) rr[r] = __shfl(rs_, 4 * g + r);
            #pragma unroll
            for (int n = 0; n < 4; ++n)
                #pragma unroll
                for (int r = 0; r < 4; ++r) oacc[n][r] *= rr[r];
            #pragma unroll
            for (int r = 0; r < 4; ++r) lacc[r] *= rr[r];
        }

        // P -> bf16 A-fragments in registers (R16 mapping)
        bf8 pa[2];
        #pragma unroll
        for (int kblk = 0; kblk < 2; ++kblk) {
            ushort2 w0 = cvt2(p[2 * kblk][0], p[2 * kblk][1]);
            ushort2 w1 = cvt2(p[2 * kblk][2], p[2 * kblk][3]);
            ushort2 w2 = cvt2(p[2 * kblk + 1][0], p[2 * kblk + 1][1]);
            ushort2 w3 = cvt2(p[2 * kblk + 1][2], p[2 * kblk + 1][3]);
            pa[kblk][0] = (short)w0.x; pa[kblk][1] = (short)w0.y;
            pa[kblk][2] = (short)w1.x; pa[kblk][3] = (short)w1.y;
            pa[kblk][4] = (short)w2.x; pa[kblk][5] = (short)w2.y;
            pa[kblk][6] = (short)w3.x; pa[kblk][7] = (short)w3.y;
        }

        if (t + 1 < nt) store_kv(bs ^ 1);   // stage tile t+1 (buffer bs^1)

        __syncthreads();                     // B1: tile t+1 LDS ready
        // ================= sec2: QK(t+1) || PV(t) =========================
        if (t + 2 < nt) load_kv((t + 2) * KVT);   // issue globals early
        __builtin_amdgcn_sched_barrier(0);
        __builtin_amdgcn_s_setprio(1);
        if (t + 1 < nt) do_qk(bs ^ 1);       // refills sacc (consumed above)

        const char* vd = (const char*)&VtB[bs][0];
        #pragma unroll
        for (int kblk = 0; kblk < 2; ++kblk) {
            const int cb = kblk * 64 + g * 16;
            #pragma unroll
            for (int n = 0; n < 4; ++n) {
                u16x4 lo = *(const u16x4*)(vd + swz8(n * 16 + a, cb));
                u16x4 hi = *(const u16x4*)(vd + swz8(n * 16 + a, cb + 8));
                bf8 vb_ = {(short)lo[0], (short)lo[1], (short)lo[2], (short)lo[3],
                           (short)hi[0], (short)hi[1], (short)hi[2], (short)hi[3]};
                oacc[n] = __builtin_amdgcn_mfma_f32_16x16x32_bf16(
                    pa[kblk], vb_, oacc[n], 0, 0, 0);
            }
            lacc = __builtin_amdgcn_mfma_f32_16x16x32_bf16(pa[kblk], ones, lacc, 0, 0, 0);
        }
        __builtin_amdgcn_s_setprio(0);
        __syncthreads();                     // B2: {K,V}[bs] reads done ->
                                             //     next iter may store into bs
    }

    // ---- epilogue: O[q=4g+r][d=16n+a] / l (lacc already row-layout) ----
    float iv[4];
    #pragma unroll
    for (int r = 0; r < 4; ++r) iv[r] = 1.0f / lacc[r];
    float* Ob = O + ((size_t)b * LQ + qbase + wid * 16) * DH;
    #pragma unroll
    for (int n = 0; n < 4; ++n)
        #pragma unroll
        for (int r = 0; r < 4; ++r)
            Ob[(size_t)(4 * g + r) * DH + 16 * n + a] = oacc[n][r] * iv[r];
}

extern "C" void kernel_launch(void* const* d_in, const int* in_sizes, int n_in,
                              void* d_out, int out_size, void* d_ws, size_t ws_size,
                              hipStream_t stream) {
    const float* Q  = (const float*)d_in[0];
    const float* K  = (const float*)d_in[1];
    const float* V  = (const float*)d_in[2];
    const int*   VL = (const int*)d_in[3];
    float* O = (float*)d_out;

    attn_v18<<<NITEMS, 512, 0, stream>>>(Q, K, V, VL, O);
}

// Round 8
// 38.173 us; speedup vs baseline: 1.0040x; 1.0039x over previous
//
#include <hip/hip_runtime.h>
#include <hip/hip_bf16.h>

// R19 = R16 (verified 33.6us) with a 128-key pair-step K-loop.
// R17 lesson: latency-bound, keep 4 waves/SIMD. R18 lesson: extra barriers
// kill inter-wave drift overlap -- keep ONE barrier per iteration.
// This round halves the per-key fixed costs (barrier, 2 ds_bpermute shfls,
// vote+rescale, loop overhead) by processing TWO 64-key tiles per iteration:
// - LDS: KsB[buf][half], VtB[buf][half] -- four VERIFIED 64x64 swz16/swz8
//   images per buffer pair; no new swizzle math. 65664 B -> 2 blocks/CU,
//   16 waves/CU (same as R16).
// - QK: 8 row-fragments; key(n,r) = 64*(n>>2)+32*((n>>1)&1)+4*(n&1)+8g+r.
// - ONE softmax per 128 keys: 32-value in-lane tree + 2 shfl + 1 vote +
//   1 rescale. exp2->pa fused per kblk (pa[kblk] from sacc[2kblk],
//   sacc[2kblk+1] -- same derivation as R16, kblk extended to 0..3).
// - PV: 4 kblk x (4 d-blocks + ones); vd half = kblk>>1.
// - Odd nt padded to full pair: K/V rows always exist (<=1024); padded keys
//   masked to -1e30 -> P=0. ~6% extra tile work, far less than overhead saved.
// - Staging identical per-64-image to R16 (role split waves 0-3 V / 4-7 K),
//   x2 tiles per iteration; same single-barrier dbuf discipline.

#define NB    64
#define LQ    1024
#define LK    1024
#define DH    64
#define KVT   64
#define KVP   128                    // pair step
#define QT    128
#define NITEMS (NB * (LQ / QT))      // 512
#define NEGF  1.0e30f
#define SC2   0.18033688011112042f   // 0.125 * log2(e)
#define THR   8.0f                   // defer-max threshold (log2 units)

typedef __attribute__((ext_vector_type(8))) short    bf8;
typedef __attribute__((ext_vector_type(8))) ushort   u16x8;
typedef __attribute__((ext_vector_type(4))) ushort   u16x4;
typedef __attribute__((ext_vector_type(4))) float    f4;

__device__ __forceinline__ ushort2 cvt2(float a, float b) {   // v_cvt_pk_bf16_f32
    float2 f; f.x = a; f.y = b;
    __hip_bfloat162 h = __float22bfloat162_rn(f);
    union { __hip_bfloat162 h2; ushort2 u2; } u;
    u.h2 = h;
    return u.u2;
}
__device__ __forceinline__ int swz16(int row, int colbyte) {  // K tile (64x64)
    return row * 128 + ((((colbyte >> 4) ^ (row & 7)) << 4) | (colbyte & 15));
}
__device__ __forceinline__ int swz8(int row, int colbyte) {   // V^T tile (64x64)
    return row * 128 + ((((colbyte >> 3) ^ (row & 15)) << 3) | (colbyte & 7));
}

__global__ __launch_bounds__(512, 4)
void attn_v19(const float* __restrict__ Q, const float* __restrict__ K,
              const float* __restrict__ V, const int* __restrict__ VL,
              float* __restrict__ O) {
    __shared__ ushort KsB[2][2][KVT * DH];  // [buf][half] swz16  32 KB
    __shared__ ushort VtB[2][2][DH * KVT];  // [buf][half] swz8   32 KB
    __shared__ ushort sched[NB];            //                     128 B => 65664

    const int tid = threadIdx.x;
    const int wid = tid >> 6, l = tid & 63, g = l >> 4, a = l & 15;

    // ---- in-kernel stratified-LPT schedule ----
    if (tid < NB) {
        const int ntb = (VL[tid] + KVT - 1) >> 6;
        int r = 0;
        for (int j = 0; j < NB; ++j) {
            const int ntj = (VL[j] + KVT - 1) >> 6;
            r += (int)((ntj > ntb) | ((ntj == ntb) & (j < tid)));
        }
        sched[r] = (ushort)tid;           // rank -> batch (desc nt, tie asc)
    }
    __syncthreads();
    const int xcd   = blockIdx.x & 7;     // HW: block i -> XCD i%8
    const int slot  = blockIdx.x >> 3;    // 0..63 within XCD
    const int qtile = slot & 7;           // 8 q-slots of 128 rows
    const int st    = slot >> 3;          // stratum 0..7
    const int rank  = xcd + ((st < 4) ? st : (11 - st)) * 8;  // pairing perm
    const int b     = sched[rank];
    const int qbase = qtile * QT;
    const int valid = VL[b];              // 1..1024
    const int nt = (valid + KVT - 1) >> 6;
    const int nu = (nt + 1) >> 1;         // pair count (pad odd nt)

    // Q fragment (B-operand), pre-scaled by SC2: col=a (q-row), k=32dk+8g+i
    const float* Qr = Q + ((size_t)b * LQ + qbase + wid * 16 + a) * DH;
    bf8 qa[2];
    #pragma unroll
    for (int dk = 0; dk < 2; ++dk) {
        f4 x = *(const f4*)(Qr + dk * 32 + g * 8);
        f4 y = *(const f4*)(Qr + dk * 32 + g * 8 + 4);
        ushort2 c0 = cvt2(x[0] * SC2, x[1] * SC2), c1 = cvt2(x[2] * SC2, x[3] * SC2);
        ushort2 c2 = cvt2(y[0] * SC2, y[1] * SC2), c3 = cvt2(y[2] * SC2, y[3] * SC2);
        qa[dk][0] = (short)c0.x; qa[dk][1] = (short)c0.y;
        qa[dk][2] = (short)c1.x; qa[dk][3] = (short)c1.y;
        qa[dk][4] = (short)c2.x; qa[dk][5] = (short)c2.y;
        qa[dk][6] = (short)c3.x; qa[dk][7] = (short)c3.y;
    }
    const bf8 ones = {0x3F80, 0x3F80, 0x3F80, 0x3F80,
                      0x3F80, 0x3F80, 0x3F80, 0x3F80};   // bf16 1.0 x8

    // staging roles: waves 0-3 stage V, waves 4-7 stage K (R16 split), x2 tiles
    const int  rtid  = tid & 255;
    const bool vrole = (wid < 4);
    const int srow = rtid >> 3, sslot = rtid & 7;   // K rows srow, srow+32
    const int vkp  = rtid >> 4, vj = rtid & 15;     // V keys 4vkp.., f4-col vj
    // physical LDS row for K key srow (<32): swap bits 3..4 with bit 2
    const int prow = (srow & 3) | ((srow & 24) >> 1) | ((srow & 4) << 2);
    const f4* Kb4 = (const f4*)(K + (size_t)b * LK * DH);
    const f4* Vb4 = (const f4*)(V + (size_t)b * LK * DH);

    f4 r0, r1, r2, r3, r4, r5, r6, r7;    // 2 tiles of staging regs
    auto load_kv2 = [&](int k0) {         // k0 = pair base (multiple of 128)
        if (vrole) {
            r0 = Vb4[(k0 + 4 * vkp + 0) * 16 + vj];
            r1 = Vb4[(k0 + 4 * vkp + 1) * 16 + vj];
            r2 = Vb4[(k0 + 4 * vkp + 2) * 16 + vj];
            r3 = Vb4[(k0 + 4 * vkp + 3) * 16 + vj];
            r4 = Vb4[(k0 + 64 + 4 * vkp + 0) * 16 + vj];
            r5 = Vb4[(k0 + 64 + 4 * vkp + 1) * 16 + vj];
            r6 = Vb4[(k0 + 64 + 4 * vkp + 2) * 16 + vj];
            r7 = Vb4[(k0 + 64 + 4 * vkp + 3) * 16 + vj];
        } else {
            r0 = Kb4[(k0 + srow) * 16 + sslot * 2];
            r1 = Kb4[(k0 + srow) * 16 + sslot * 2 + 1];
            r2 = Kb4[(k0 + srow + 32) * 16 + sslot * 2];
            r3 = Kb4[(k0 + srow + 32) * 16 + sslot * 2 + 1];
            r4 = Kb4[(k0 + 64 + srow) * 16 + sslot * 2];
            r5 = Kb4[(k0 + 64 + srow) * 16 + sslot * 2 + 1];
            r6 = Kb4[(k0 + 64 + srow + 32) * 16 + sslot * 2];
            r7 = Kb4[(k0 + 64 + srow + 32) * 16 + sslot * 2 + 1];
        }
    };
    auto store_half = [&](int bs, int h, f4 a0, f4 a1, f4 a2, f4 a3) {
        if (vrole) {
            char* vd = (char*)&VtB[bs][h][0];
            #pragma unroll
            for (int c = 0; c < 4; ++c) {      // transpose: d = 4*vj+c
                ushort2 a01 = cvt2(a0[c], a1[c]), a23 = cvt2(a2[c], a3[c]);
                u16x4 p = {a01.x, a01.y, a23.x, a23.y};
                *(u16x4*)(vd + swz8(4 * vj + c, vkp * 8)) = p;
            }
        } else {
            char* kd = (char*)&KsB[bs][h][0];
            {
                ushort2 c0 = cvt2(a0[0], a0[1]), c1 = cvt2(a0[2], a0[3]);
                ushort2 c2 = cvt2(a1[0], a1[1]), c3 = cvt2(a1[2], a1[3]);
                u16x8 w = {c0.x, c0.y, c1.x, c1.y, c2.x, c2.y, c3.x, c3.y};
                *(u16x8*)(kd + swz16(prow, sslot * 16)) = w;
            }
            {
                ushort2 c0 = cvt2(a2[0], a2[1]), c1 = cvt2(a2[2], a2[3]);
                ushort2 c2 = cvt2(a3[0], a3[1]), c3 = cvt2(a3[2], a3[3]);
                u16x8 w = {c0.x, c0.y, c1.x, c1.y, c2.x, c2.y, c3.x, c3.y};
                *(u16x8*)(kd + swz16(prow + 32, sslot * 16)) = w;
            }
        }
    };
    auto store_kv2 = [&](int bs) {
        store_half(bs, 0, r0, r1, r2, r3);
        store_half(bs, 1, r4, r5, r6, r7);
    };

    f4 oacc[4];
    #pragma unroll
    for (int n = 0; n < 4; ++n) oacc[n] = f4{0.f, 0.f, 0.f, 0.f};
    f4 lacc = f4{0.f, 0.f, 0.f, 0.f};   // l per q-row 4g+r (epilogue layout)
    float m_run = -NEGF;                // per-lane: q-row = a

    load_kv2(0);
    store_kv2(0);
    for (int u = 0; u < nu; ++u) {
        const int bs = u & 1;
        __syncthreads();                          // buf[bs] ready block-wide
        if (u + 1 < nu) load_kv2((u + 1) * KVP);  // issue early...
        __builtin_amdgcn_sched_barrier(0);        // ...keep it early

        // ---- S^T over 128 keys: lane (g,a) fragment n holds
        //      S[q=a][key = 64*(n>>2)+32*((n>>1)&1)+4*(n&1)+8g+r] ----
        f4 sacc[8];
        #pragma unroll
        for (int n = 0; n < 8; ++n) sacc[n] = f4{0.f, 0.f, 0.f, 0.f};
        __builtin_amdgcn_s_setprio(1);
        #pragma unroll
        for (int n = 0; n < 8; ++n) {
            const char* kd = (const char*)&KsB[bs][n >> 2][0];
            const int row = (n & 3) * 16 + a;
            #pragma unroll
            for (int dk = 0; dk < 2; ++dk) {
                bf8 kb = *(const bf8*)(kd + swz16(row, dk * 64 + g * 16));
                sacc[n] = __builtin_amdgcn_mfma_f32_16x16x32_bf16(
                    kb, qa[dk], sacc[n], 0, 0, 0);   // A=K, B=Q
            }
        }
        __builtin_amdgcn_s_setprio(0);

        // ---- mask (in place) ----
        const int kmax = valid - u * KVP;
        if (kmax < KVP) {
            #pragma unroll
            for (int n = 0; n < 8; ++n) {
                const int kb_ = 64 * (n >> 2) + 32 * ((n >> 1) & 1) + 4 * (n & 1);
                #pragma unroll
                for (int r = 0; r < 4; ++r)
                    if (kb_ + 8 * g + r >= kmax) sacc[n][r] = -NEGF;
            }
        }

        // ---- softmax max: in-lane tree over 32 + 2 shfl over g ----
        float mn[8];
        #pragma unroll
        for (int n = 0; n < 8; ++n)
            mn[n] = fmaxf(fmaxf(sacc[n][0], sacc[n][1]),
                          fmaxf(sacc[n][2], sacc[n][3]));
        float t0 = fmaxf(fmaxf(mn[0], mn[1]), fmaxf(mn[2], mn[3]));
        float t1 = fmaxf(fmaxf(mn[4], mn[5]), fmaxf(mn[6], mn[7]));
        float tm = fmaxf(t0, t1);
        tm = fmaxf(tm, __shfl_xor(tm, 16));
        tm = fmaxf(tm, __shfl_xor(tm, 32));

        float rs_ = 1.0f;                     // T13 defer-max
        const bool skip = __all(tm <= m_run + THR);
        if (!skip) {
            const float mnew = fmaxf(m_run, tm);
            rs_ = __builtin_exp2f(m_run - mnew);   // pair0: exp2(-inf)=0
            m_run = mnew;
        }
        if (!skip) {   // rescale O,l rows (q=4g+r)
            float rr[4];
            #pragma unroll
            for (int r = 0; r < 4; ++r) rr[r] = __shfl(rs_, 4 * g + r);
            #pragma unroll
            for (int n = 0; n < 4; ++n)
                #pragma unroll
                for (int r = 0; r < 4; ++r) oacc[n][r] *= rr[r];
            #pragma unroll
            for (int r = 0; r < 4; ++r) lacc[r] *= rr[r];
        }

        // ---- O += P V ; l += P * ones  (P built in-register per kblk) ----
        // pa[kblk] covers keys 32kblk+8g+i: i=0..3 from sacc[2kblk][r],
        // i=4..7 from sacc[2kblk+1][r]  (same derivation as R16).
        __builtin_amdgcn_s_setprio(1);
        #pragma unroll
        for (int kblk = 0; kblk < 4; ++kblk) {
            float p0[4], p1[4];
            #pragma unroll
            for (int r = 0; r < 4; ++r) {
                p0[r] = __builtin_exp2f(sacc[2 * kblk][r] - m_run);
                p1[r] = __builtin_exp2f(sacc[2 * kblk + 1][r] - m_run);
            }
            ushort2 w0 = cvt2(p0[0], p0[1]), w1 = cvt2(p0[2], p0[3]);
            ushort2 w2 = cvt2(p1[0], p1[1]), w3 = cvt2(p1[2], p1[3]);
            bf8 pa = {(short)w0.x, (short)w0.y, (short)w1.x, (short)w1.y,
                      (short)w2.x, (short)w2.y, (short)w3.x, (short)w3.y};
            const char* vd = (const char*)&VtB[bs][kblk >> 1][0];
            const int cb = (kblk & 1) * 64 + g * 16;
            #pragma unroll
            for (int n = 0; n < 4; ++n) {
                u16x4 lo = *(const u16x4*)(vd + swz8(n * 16 + a, cb));
                u16x4 hi = *(const u16x4*)(vd + swz8(n * 16 + a, cb + 8));
                bf8 vb_ = {(short)lo[0], (short)lo[1], (short)lo[2], (short)lo[3],
                           (short)hi[0], (short)hi[1], (short)hi[2], (short)hi[3]};
                oacc[n] = __builtin_amdgcn_mfma_f32_16x16x32_bf16(
                    pa, vb_, oacc[n], 0, 0, 0);
            }
            lacc = __builtin_amdgcn_mfma_f32_16x16x32_bf16(pa, ones, lacc, 0, 0, 0);
        }
        __builtin_amdgcn_s_setprio(0);

        if (u + 1 < nu) store_kv2(bs ^ 1);   // post-compute, pre-next-barrier
    }

    // ---- epilogue: O[q=4g+r][d=16n+a] / l (lacc already row-layout) ----
    float iv[4];
    #pragma unroll
    for (int r = 0; r < 4; ++r) iv[r] = 1.0f / lacc[r];
    float* Ob = O + ((size_t)b * LQ + qbase + wid * 16) * DH;
    #pragma unroll
    for (int n = 0; n < 4; ++n)
        #pragma unroll
        for (int r = 0; r < 4; ++r)
            Ob[(size_t)(4 * g + r) * DH + 16 * n + a] = oacc[n][r] * iv[r];
}

extern "C" void kernel_launch(void* const* d_in, const int* in_sizes, int n_in,
                              void* d_out, int out_size, void* d_ws, size_t ws_size,
                              hipStream_t stream) {
    const float* Q  = (const float*)d_in[0];
    const float* K  = (const float*)d_in[1];
    const float* V  = (const float*)d_in[2];
    const int*   VL = (const int*)d_in[3];
    float* O = (float*)d_out;

    attn_v19<<<NITEMS, 512, 0, stream>>>(Q, K, V, VL, O);
}

// Round 9
// 34.079 us; speedup vs baseline: 1.1246x; 1.1201x over previous
//
#include <hip/hip_runtime.h>
#include <hip/hip_bf16.h>

// R20 = R16 (verified 33.6us champion) + ONE micro-delta: V^T tile moves from
// swz8 to swz16 layout so each PV V-fragment is a SINGLE ds_read_b128 that IS
// the bf8 operand (16 contiguous bytes = keys kblk*32+8g..+7 of d-row n*16+a).
// Removes per wave-tile: 8 LDS issues (16 b64 -> 8 b128), 8 addr calcs, and
// the lo/hi->bf8 assembly. Read pattern becomes identical to the verified
// K-read pattern (row=n*16+a, col=kblk*64+g*16). Staging V writes u16x4 at
// swz16(4vj+c, vkp*8): ~2-way write aliasing (free per m136) vs swz8's
// conflict-free -- small cost vs the read-side win.
// Structure lessons locked in from R17/R18/R19 (all regressed to ~38.2):
// keep 8 waves x 16 q-rows, ONE barrier/tile, minimal live state, loose loop.
// Values/rounding/MFMA order unchanged -> output bit-identical to R16.

#define NB    64
#define LQ    1024
#define LK    1024
#define DH    64
#define KVT   64
#define QT    128
#define NITEMS (NB * (LQ / QT))      // 512
#define NEGF  1.0e30f
#define SC2   0.18033688011112042f   // 0.125 * log2(e)
#define THR   8.0f                   // defer-max threshold (log2 units)

typedef __attribute__((ext_vector_type(8))) short    bf8;
typedef __attribute__((ext_vector_type(8))) ushort   u16x8;
typedef __attribute__((ext_vector_type(4))) ushort   u16x4;
typedef __attribute__((ext_vector_type(4))) float    f4;

__device__ __forceinline__ ushort2 cvt2(float a, float b) {   // v_cvt_pk_bf16_f32
    float2 f; f.x = a; f.y = b;
    __hip_bfloat162 h = __float22bfloat162_rn(f);
    union { __hip_bfloat162 h2; ushort2 u2; } u;
    u.h2 = h;
    return u.u2;
}
__device__ __forceinline__ int swz16(int row, int colbyte) {  // K, V^T tiles
    return row * 128 + ((((colbyte >> 4) ^ (row & 7)) << 4) | (colbyte & 15));
}

__global__ __launch_bounds__(512, 4)
void attn_v20(const float* __restrict__ Q, const float* __restrict__ K,
              const float* __restrict__ V, const int* __restrict__ VL,
              float* __restrict__ O) {
    __shared__ ushort KsB[2][KVT * DH];   // swz16 [phys key][d] 16 KB
    __shared__ ushort VtB[2][DH * KVT];   // swz16 [d][key]      16 KB
    __shared__ ushort sched[NB];          // rank -> batch        128 B => 32896

    const int tid = threadIdx.x;
    const int wid = tid >> 6, l = tid & 63, g = l >> 4, a = l & 15;

    // ---- in-kernel stratified-LPT schedule ----
    if (tid < NB) {
        const int ntb = (VL[tid] + KVT - 1) >> 6;
        int r = 0;
        for (int j = 0; j < NB; ++j) {
            const int ntj = (VL[j] + KVT - 1) >> 6;
            r += (int)((ntj > ntb) | ((ntj == ntb) & (j < tid)));
        }
        sched[r] = (ushort)tid;           // rank -> batch (desc nt, tie asc)
    }
    __syncthreads();
    const int xcd   = blockIdx.x & 7;     // HW: block i -> XCD i%8
    const int slot  = blockIdx.x >> 3;    // 0..63 within XCD
    const int qtile = slot & 7;           // 8 q-slots of 128 rows
    const int st    = slot >> 3;          // stratum 0..7
    // pairing perm8={0,1,2,3,7,6,5,4}: CU gets complementary strata
    const int rank  = xcd + ((st < 4) ? st : (11 - st)) * 8;
    const int b     = sched[rank];
    const int qbase = qtile * QT;
    const int valid = VL[b];              // 1..1024
    const int nt = (valid + KVT - 1) >> 6;

    // Q fragment (B-operand), pre-scaled by SC2: col=a (q-row), k=32kblk+8g+i
    const float* Qr = Q + ((size_t)b * LQ + qbase + wid * 16 + a) * DH;
    bf8 qa[2];
    #pragma unroll
    for (int kblk = 0; kblk < 2; ++kblk) {
        f4 x = *(const f4*)(Qr + kblk * 32 + g * 8);
        f4 y = *(const f4*)(Qr + kblk * 32 + g * 8 + 4);
        ushort2 c0 = cvt2(x[0] * SC2, x[1] * SC2), c1 = cvt2(x[2] * SC2, x[3] * SC2);
        ushort2 c2 = cvt2(y[0] * SC2, y[1] * SC2), c3 = cvt2(y[2] * SC2, y[3] * SC2);
        qa[kblk][0] = (short)c0.x; qa[kblk][1] = (short)c0.y;
        qa[kblk][2] = (short)c1.x; qa[kblk][3] = (short)c1.y;
        qa[kblk][4] = (short)c2.x; qa[kblk][5] = (short)c2.y;
        qa[kblk][6] = (short)c3.x; qa[kblk][7] = (short)c3.y;
    }
    const bf8 ones = {0x3F80, 0x3F80, 0x3F80, 0x3F80,
                      0x3F80, 0x3F80, 0x3F80, 0x3F80};   // bf16 1.0 x8

    // staging roles: waves 0-3 stage V, waves 4-7 stage K (R16 split)
    const int  rtid  = tid & 255;
    const bool vrole = (wid < 4);
    const int srow = rtid >> 3, sslot = rtid & 7;   // K rows srow, srow+32
    const int vkp  = rtid >> 4, vj = rtid & 15;     // V keys 4vkp.., f4-col vj
    // physical LDS row for K key srow (<32): swap bits 3..4 with bit 2
    const int prow = (srow & 3) | ((srow & 24) >> 1) | ((srow & 4) << 2);
    const f4* Kb4 = (const f4*)(K + (size_t)b * LK * DH);
    const f4* Vb4 = (const f4*)(V + (size_t)b * LK * DH);

    f4 r0, r1, r2, r3;
    auto load_kv = [&](int k0) {
        if (vrole) {
            r0 = Vb4[(k0 + 4 * vkp + 0) * 16 + vj];
            r1 = Vb4[(k0 + 4 * vkp + 1) * 16 + vj];
            r2 = Vb4[(k0 + 4 * vkp + 2) * 16 + vj];
            r3 = Vb4[(k0 + 4 * vkp + 3) * 16 + vj];
        } else {
            r0 = Kb4[(k0 + srow) * 16 + sslot * 2];
            r1 = Kb4[(k0 + srow) * 16 + sslot * 2 + 1];
            r2 = Kb4[(k0 + srow + 32) * 16 + sslot * 2];
            r3 = Kb4[(k0 + srow + 32) * 16 + sslot * 2 + 1];
        }
    };
    auto store_kv = [&](int bs) {
        if (vrole) {
            char* vd = (char*)&VtB[bs][0];
            #pragma unroll
            for (int c = 0; c < 4; ++c) {      // transpose: d = 4*vj+c
                ushort2 a01 = cvt2(r0[c], r1[c]), a23 = cvt2(r2[c], r3[c]);
                u16x4 p = {a01.x, a01.y, a23.x, a23.y};
                *(u16x4*)(vd + swz16(4 * vj + c, vkp * 8)) = p;   // swz16 now
            }
        } else {
            char* kd = (char*)&KsB[bs][0];
            {
                ushort2 c0 = cvt2(r0[0], r0[1]), c1 = cvt2(r0[2], r0[3]);
                ushort2 c2 = cvt2(r1[0], r1[1]), c3 = cvt2(r1[2], r1[3]);
                u16x8 w = {c0.x, c0.y, c1.x, c1.y, c2.x, c2.y, c3.x, c3.y};
                *(u16x8*)(kd + swz16(prow, sslot * 16)) = w;
            }
            {
                ushort2 c0 = cvt2(r2[0], r2[1]), c1 = cvt2(r2[2], r2[3]);
                ushort2 c2 = cvt2(r3[0], r3[1]), c3 = cvt2(r3[2], r3[3]);
                u16x8 w = {c0.x, c0.y, c1.x, c1.y, c2.x, c2.y, c3.x, c3.y};
                *(u16x8*)(kd + swz16(prow + 32, sslot * 16)) = w;
            }
        }
    };

    f4 oacc[4];
    #pragma unroll
    for (int n = 0; n < 4; ++n) oacc[n] = f4{0.f, 0.f, 0.f, 0.f};
    f4 lacc = f4{0.f, 0.f, 0.f, 0.f};   // l per q-row 4g+r (epilogue layout)
    float m_run = -NEGF;                // per-lane: q-row = a

    load_kv(0);
    store_kv(0);
    for (int t = 0; t < nt; ++t) {
        const int bs = t & 1;
        __syncthreads();                         // buf[bs] ready block-wide
        if (t + 1 < nt) load_kv((t + 1) * KVT);  // issue early...
        __builtin_amdgcn_sched_barrier(0);       // ...keep it early

        // ---- S^T = K Q^T: phys rows n*16+a => lane (g,a) holds
        //      S[q=a][key = 32*(n>>1) + 4*(n&1) + 8g + r] ----
        const char* kd = (const char*)&KsB[bs][0];
        f4 sacc[4];
        #pragma unroll
        for (int n = 0; n < 4; ++n) sacc[n] = f4{0.f, 0.f, 0.f, 0.f};
        __builtin_amdgcn_s_setprio(1);
        #pragma unroll
        for (int n = 0; n < 4; ++n)
            #pragma unroll
            for (int kblk = 0; kblk < 2; ++kblk) {
                bf8 kb = *(const bf8*)(kd + swz16(n * 16 + a, kblk * 64 + g * 16));
                sacc[n] = __builtin_amdgcn_mfma_f32_16x16x32_bf16(
                    kb, qa[kblk], sacc[n], 0, 0, 0);   // A=K, B=Q
            }
        __builtin_amdgcn_s_setprio(0);

        float s[4][4];
        const int kmax = valid - t * KVT;
        #pragma unroll
        for (int n = 0; n < 4; ++n)
            #pragma unroll
            for (int r = 0; r < 4; ++r) s[n][r] = sacc[n][r];
        if (kmax < KVT) {
            #pragma unroll
            for (int n = 0; n < 4; ++n)
                #pragma unroll
                for (int r = 0; r < 4; ++r)
                    if (32 * (n >> 1) + 4 * (n & 1) + 8 * g + r >= kmax)
                        s[n][r] = -NEGF;
        }

        // ---- softmax max: in-lane tree (depth 4) + 2 shfl over g ----
        float m0 = fmaxf(fmaxf(s[0][0], s[0][1]), fmaxf(s[0][2], s[0][3]));
        float m1 = fmaxf(fmaxf(s[1][0], s[1][1]), fmaxf(s[1][2], s[1][3]));
        float m2 = fmaxf(fmaxf(s[2][0], s[2][1]), fmaxf(s[2][2], s[2][3]));
        float m3 = fmaxf(fmaxf(s[3][0], s[3][1]), fmaxf(s[3][2], s[3][3]));
        float tm = fmaxf(fmaxf(m0, m1), fmaxf(m2, m3));
        tm = fmaxf(tm, __shfl_xor(tm, 16));
        tm = fmaxf(tm, __shfl_xor(tm, 32));

        float rs_ = 1.0f;                     // T13 defer-max
        const bool skip = __all(tm <= m_run + THR);
        if (!skip) {
            const float mnew = fmaxf(m_run, tm);
            rs_ = __builtin_exp2f(m_run - mnew);   // tile0: exp2(-inf)=0
            m_run = mnew;
        }

        float p[4][4];
        #pragma unroll
        for (int n = 0; n < 4; ++n)
            #pragma unroll
            for (int r = 0; r < 4; ++r)
                p[n][r] = __builtin_exp2f(s[n][r] - m_run);   // masked -> 0

        if (!skip) {   // rescale O,l rows (q=4g+r)
            float rr[4];
            #pragma unroll
            for (int r = 0; r < 4; ++r) rr[r] = __shfl(rs_, 4 * g + r);
            #pragma unroll
            for (int n = 0; n < 4; ++n)
                #pragma unroll
                for (int r = 0; r < 4; ++r) oacc[n][r] *= rr[r];
            #pragma unroll
            for (int r = 0; r < 4; ++r) lacc[r] *= rr[r];
        }

        // ---- O += P V ; l += P * ones  (P in registers; vb = ONE b128) ----
        // pa[kblk] = A[row=a][k = 32kblk + 8g + i]: i=0..3 from p[2kblk][r],
        // i=4..7 from p[2kblk+1][r].
        const char* vd = (const char*)&VtB[bs][0];
        __builtin_amdgcn_s_setprio(1);
        #pragma unroll
        for (int kblk = 0; kblk < 2; ++kblk) {
            ushort2 w0 = cvt2(p[2 * kblk][0], p[2 * kblk][1]);
            ushort2 w1 = cvt2(p[2 * kblk][2], p[2 * kblk][3]);
            ushort2 w2 = cvt2(p[2 * kblk + 1][0], p[2 * kblk + 1][1]);
            ushort2 w3 = cvt2(p[2 * kblk + 1][2], p[2 * kblk + 1][3]);
            bf8 pa = {(short)w0.x, (short)w0.y, (short)w1.x, (short)w1.y,
                      (short)w2.x, (short)w2.y, (short)w3.x, (short)w3.y};
            const int cb = kblk * 64 + g * 16;
            #pragma unroll
            for (int n = 0; n < 4; ++n) {
                bf8 vb_ = *(const bf8*)(vd + swz16(n * 16 + a, cb)); // b128 direct
                oacc[n] = __builtin_amdgcn_mfma_f32_16x16x32_bf16(
                    pa, vb_, oacc[n], 0, 0, 0);
            }
            lacc = __builtin_amdgcn_mfma_f32_16x16x32_bf16(pa, ones, lacc, 0, 0, 0);
        }
        __builtin_amdgcn_s_setprio(0);

        if (t + 1 < nt) store_kv(bs ^ 1);   // post-compute, pre-next-barrier
    }

    // ---- epilogue: O[q=4g+r][d=16n+a] / l (lacc already row-layout) ----
    float iv[4];
    #pragma unroll
    for (int r = 0; r < 4; ++r) iv[r] = 1.0f / lacc[r];
    float* Ob = O + ((size_t)b * LQ + qbase + wid * 16) * DH;
    #pragma unroll
    for (int n = 0; n < 4; ++n)
        #pragma unroll
        for (int r = 0; r < 4; ++r)
            Ob[(size_t)(4 * g + r) * DH + 16 * n + a] = oacc[n][r] * iv[r];
}

extern "C" void kernel_launch(void* const* d_in, const int* in_sizes, int n_in,
                              void* d_out, int out_size, void* d_ws, size_t ws_size,
                              hipStream_t stream) {
    const float* Q  = (const float*)d_in[0];
    const float* K  = (const float*)d_in[1];
    const float* V  = (const float*)d_in[2];
    const int*   VL = (const int*)d_in[3];
    float* O = (float*)d_out;

    attn_v20<<<NITEMS, 512, 0, stream>>>(Q, K, V, VL, O);
}

// Round 10
// 33.059 us; speedup vs baseline: 1.1593x; 1.0309x over previous
//
#include <hip/hip_runtime.h>
#include <hip/hip_bf16.h>

// R21 = R20 + address-hoist + unroll-2 (static buffer index) + in-place mask.
// Theory: per wave-tile ~96 VALU insts + 16 exp2 vs 2350-cyc period (42%
// VALUBusy); ~32 of those insts are LOOP-INVARIANT LDS addr recomputation.
// In R20's layout K-reads and V-reads share the SAME offset formula
// swz16(n*16+a, kblk*64+g*16) -> ONE set of 8 precomputed offsets serves all
// 16 ds_read_b128 per tile. Unrolling the K-loop by 2 makes bs literal, so
// &KsB[bs]/&VtB[bs] fold into the ds_read immediate: zero per-read addr VALU.
// Also: mask applied in place on sacc (kills 16-mov copy); max tree nested
// 3-ary for v_max3 fusion. Sync structure, barrier count, MFMA order, and all
// roundings identical to R20 -> output bit-identical.

#define NB    64
#define LQ    1024
#define LK    1024
#define DH    64
#define KVT   64
#define QT    128
#define NITEMS (NB * (LQ / QT))      // 512
#define NEGF  1.0e30f
#define SC2   0.18033688011112042f   // 0.125 * log2(e)
#define THR   8.0f                   // defer-max threshold (log2 units)

typedef __attribute__((ext_vector_type(8))) short    bf8;
typedef __attribute__((ext_vector_type(8))) ushort   u16x8;
typedef __attribute__((ext_vector_type(4))) ushort   u16x4;
typedef __attribute__((ext_vector_type(4))) float    f4;

__device__ __forceinline__ ushort2 cvt2(float a, float b) {   // v_cvt_pk_bf16_f32
    float2 f; f.x = a; f.y = b;
    __hip_bfloat162 h = __float22bfloat162_rn(f);
    union { __hip_bfloat162 h2; ushort2 u2; } u;
    u.h2 = h;
    return u.u2;
}
__device__ __forceinline__ int swz16(int row, int colbyte) {  // K, V^T tiles
    return row * 128 + ((((colbyte >> 4) ^ (row & 7)) << 4) | (colbyte & 15));
}
__device__ __forceinline__ float fm3(float a, float b, float c) {  // v_max3
    return fmaxf(fmaxf(a, b), c);
}

__global__ __launch_bounds__(512, 4)
void attn_v21(const float* __restrict__ Q, const float* __restrict__ K,
              const float* __restrict__ V, const int* __restrict__ VL,
              float* __restrict__ O) {
    __shared__ ushort KsB[2][KVT * DH];   // swz16 [phys key][d] 16 KB
    __shared__ ushort VtB[2][DH * KVT];   // swz16 [d][key]      16 KB
    __shared__ ushort sched[NB];          // rank -> batch        128 B => 32896

    const int tid = threadIdx.x;
    const int wid = tid >> 6, l = tid & 63, g = l >> 4, a = l & 15;

    // ---- in-kernel stratified-LPT schedule ----
    if (tid < NB) {
        const int ntb = (VL[tid] + KVT - 1) >> 6;
        int r = 0;
        for (int j = 0; j < NB; ++j) {
            const int ntj = (VL[j] + KVT - 1) >> 6;
            r += (int)((ntj > ntb) | ((ntj == ntb) & (j < tid)));
        }
        sched[r] = (ushort)tid;           // rank -> batch (desc nt, tie asc)
    }
    __syncthreads();
    const int xcd   = blockIdx.x & 7;     // HW: block i -> XCD i%8
    const int slot  = blockIdx.x >> 3;    // 0..63 within XCD
    const int qtile = slot & 7;           // 8 q-slots of 128 rows
    const int st    = slot >> 3;          // stratum 0..7
    // pairing perm8={0,1,2,3,7,6,5,4}: CU gets complementary strata
    const int rank  = xcd + ((st < 4) ? st : (11 - st)) * 8;
    const int b     = sched[rank];
    const int qbase = qtile * QT;
    const int valid = VL[b];              // 1..1024
    const int nt = (valid + KVT - 1) >> 6;

    // Hoisted LDS read offsets: same formula serves K and V reads.
    int off8[8];                          // [n][kblk] -> n*2 + kblk
    #pragma unroll
    for (int n = 0; n < 4; ++n)
        #pragma unroll
        for (int kblk = 0; kblk < 2; ++kblk)
            off8[n * 2 + kblk] = swz16(n * 16 + a, kblk * 64 + g * 16);

    // Q fragment (B-operand), pre-scaled by SC2: col=a (q-row), k=32kblk+8g+i
    const float* Qr = Q + ((size_t)b * LQ + qbase + wid * 16 + a) * DH;
    bf8 qa[2];
    #pragma unroll
    for (int kblk = 0; kblk < 2; ++kblk) {
        f4 x = *(const f4*)(Qr + kblk * 32 + g * 8);
        f4 y = *(const f4*)(Qr + kblk * 32 + g * 8 + 4);
        ushort2 c0 = cvt2(x[0] * SC2, x[1] * SC2), c1 = cvt2(x[2] * SC2, x[3] * SC2);
        ushort2 c2 = cvt2(y[0] * SC2, y[1] * SC2), c3 = cvt2(y[2] * SC2, y[3] * SC2);
        qa[kblk][0] = (short)c0.x; qa[kblk][1] = (short)c0.y;
        qa[kblk][2] = (short)c1.x; qa[kblk][3] = (short)c1.y;
        qa[kblk][4] = (short)c2.x; qa[kblk][5] = (short)c2.y;
        qa[kblk][6] = (short)c3.x; qa[kblk][7] = (short)c3.y;
    }
    const bf8 ones = {0x3F80, 0x3F80, 0x3F80, 0x3F80,
                      0x3F80, 0x3F80, 0x3F80, 0x3F80};   // bf16 1.0 x8

    // staging roles: waves 0-3 stage V, waves 4-7 stage K (R16 split)
    const int  rtid  = tid & 255;
    const bool vrole = (wid < 4);
    const int srow = rtid >> 3, sslot = rtid & 7;   // K rows srow, srow+32
    const int vkp  = rtid >> 4, vj = rtid & 15;     // V keys 4vkp.., f4-col vj
    // physical LDS row for K key srow (<32): swap bits 3..4 with bit 2
    const int prow = (srow & 3) | ((srow & 24) >> 1) | ((srow & 4) << 2);
    const f4* Kb4 = (const f4*)(K + (size_t)b * LK * DH);
    const f4* Vb4 = (const f4*)(V + (size_t)b * LK * DH);

    f4 r0, r1, r2, r3;
    auto load_kv = [&](int k0) {
        if (vrole) {
            r0 = Vb4[(k0 + 4 * vkp + 0) * 16 + vj];
            r1 = Vb4[(k0 + 4 * vkp + 1) * 16 + vj];
            r2 = Vb4[(k0 + 4 * vkp + 2) * 16 + vj];
            r3 = Vb4[(k0 + 4 * vkp + 3) * 16 + vj];
        } else {
            r0 = Kb4[(k0 + srow) * 16 + sslot * 2];
            r1 = Kb4[(k0 + srow) * 16 + sslot * 2 + 1];
            r2 = Kb4[(k0 + srow + 32) * 16 + sslot * 2];
            r3 = Kb4[(k0 + srow + 32) * 16 + sslot * 2 + 1];
        }
    };
    auto store_kv = [&](int bs) {
        if (vrole) {
            char* vd = (char*)&VtB[bs][0];
            #pragma unroll
            for (int c = 0; c < 4; ++c) {      // transpose: d = 4*vj+c
                ushort2 a01 = cvt2(r0[c], r1[c]), a23 = cvt2(r2[c], r3[c]);
                u16x4 p = {a01.x, a01.y, a23.x, a23.y};
                *(u16x4*)(vd + swz16(4 * vj + c, vkp * 8)) = p;
            }
        } else {
            char* kd = (char*)&KsB[bs][0];
            {
                ushort2 c0 = cvt2(r0[0], r0[1]), c1 = cvt2(r0[2], r0[3]);
                ushort2 c2 = cvt2(r1[0], r1[1]), c3 = cvt2(r1[2], r1[3]);
                u16x8 w = {c0.x, c0.y, c1.x, c1.y, c2.x, c2.y, c3.x, c3.y};
                *(u16x8*)(kd + swz16(prow, sslot * 16)) = w;
            }
            {
                ushort2 c0 = cvt2(r2[0], r2[1]), c1 = cvt2(r2[2], r2[3]);
                ushort2 c2 = cvt2(r3[0], r3[1]), c3 = cvt2(r3[2], r3[3]);
                u16x8 w = {c0.x, c0.y, c1.x, c1.y, c2.x, c2.y, c3.x, c3.y};
                *(u16x8*)(kd + swz16(prow + 32, sslot * 16)) = w;
            }
        }
    };

    f4 oacc[4];
    #pragma unroll
    for (int n = 0; n < 4; ++n) oacc[n] = f4{0.f, 0.f, 0.f, 0.f};
    f4 lacc = f4{0.f, 0.f, 0.f, 0.f};   // l per q-row 4g+r (epilogue layout)
    float m_run = -NEGF;                // per-lane: q-row = a

    // One tile iteration; bs is a LITERAL at every callsite so the LDS base
    // folds into ds_read/ds_write immediates.
    auto tile_iter = [&](int t, const int bs) {
        __syncthreads();                         // buf[bs] ready block-wide
        if (t + 1 < nt) load_kv((t + 1) * KVT);  // issue early...
        __builtin_amdgcn_sched_barrier(0);       // ...keep it early

        // ---- S^T = K Q^T: lane (g,a) holds S[q=a][key=32(n>>1)+4(n&1)+8g+r]
        const char* kd = (const char*)&KsB[bs][0];
        f4 sacc[4];
        #pragma unroll
        for (int n = 0; n < 4; ++n) sacc[n] = f4{0.f, 0.f, 0.f, 0.f};
        __builtin_amdgcn_s_setprio(1);
        #pragma unroll
        for (int n = 0; n < 4; ++n)
            #pragma unroll
            for (int kblk = 0; kblk < 2; ++kblk) {
                bf8 kb = *(const bf8*)(kd + off8[n * 2 + kblk]);
                sacc[n] = __builtin_amdgcn_mfma_f32_16x16x32_bf16(
                    kb, qa[kblk], sacc[n], 0, 0, 0);   // A=K, B=Q
            }
        __builtin_amdgcn_s_setprio(0);

        // ---- mask in place ----
        const int kmax = valid - t * KVT;
        if (kmax < KVT) {
            #pragma unroll
            for (int n = 0; n < 4; ++n)
                #pragma unroll
                for (int r = 0; r < 4; ++r)
                    if (32 * (n >> 1) + 4 * (n & 1) + 8 * g + r >= kmax)
                        sacc[n][r] = -NEGF;
        }

        // ---- softmax max: 3-ary tree (v_max3) + 2 shfl over g ----
        float t0 = fm3(sacc[0][0], sacc[0][1], sacc[0][2]);
        float t1 = fm3(sacc[0][3], sacc[1][0], sacc[1][1]);
        float t2 = fm3(sacc[1][2], sacc[1][3], sacc[2][0]);
        float t3 = fm3(sacc[2][1], sacc[2][2], sacc[2][3]);
        float t4 = fm3(sacc[3][0], sacc[3][1], sacc[3][2]);
        float tm = fm3(fm3(t0, t1, t2), fm3(t3, t4, sacc[3][3]),
                       -NEGF);
        tm = fmaxf(tm, __shfl_xor(tm, 16));
        tm = fmaxf(tm, __shfl_xor(tm, 32));

        float rs_ = 1.0f;                     // T13 defer-max
        const bool skip = __all(tm <= m_run + THR);
        if (!skip) {
            const float mnew = fmaxf(m_run, tm);
            rs_ = __builtin_exp2f(m_run - mnew);   // tile0: exp2(-inf)=0
            m_run = mnew;
        }

        float p[4][4];
        #pragma unroll
        for (int n = 0; n < 4; ++n)
            #pragma unroll
            for (int r = 0; r < 4; ++r)
                p[n][r] = __builtin_exp2f(sacc[n][r] - m_run);   // masked -> 0

        if (!skip) {   // rescale O,l rows (q=4g+r)
            float rr[4];
            #pragma unroll
            for (int r = 0; r < 4; ++r) rr[r] = __shfl(rs_, 4 * g + r);
            #pragma unroll
            for (int n = 0; n < 4; ++n)
                #pragma unroll
                for (int r = 0; r < 4; ++r) oacc[n][r] *= rr[r];
            #pragma unroll
            for (int r = 0; r < 4; ++r) lacc[r] *= rr[r];
        }

        // ---- O += P V ; l += P * ones  (P in registers; vb one b128) ----
        const char* vd = (const char*)&VtB[bs][0];
        __builtin_amdgcn_s_setprio(1);
        #pragma unroll
        for (int kblk = 0; kblk < 2; ++kblk) {
            ushort2 w0 = cvt2(p[2 * kblk][0], p[2 * kblk][1]);
            ushort2 w1 = cvt2(p[2 * kblk][2], p[2 * kblk][3]);
            ushort2 w2 = cvt2(p[2 * kblk + 1][0], p[2 * kblk + 1][1]);
            ushort2 w3 = cvt2(p[2 * kblk + 1][2], p[2 * kblk + 1][3]);
            bf8 pa = {(short)w0.x, (short)w0.y, (short)w1.x, (short)w1.y,
                      (short)w2.x, (short)w2.y, (short)w3.x, (short)w3.y};
            #pragma unroll
            for (int n = 0; n < 4; ++n) {
                bf8 vb_ = *(const bf8*)(vd + off8[n * 2 + kblk]);
                oacc[n] = __builtin_amdgcn_mfma_f32_16x16x32_bf16(
                    pa, vb_, oacc[n], 0, 0, 0);
            }
            lacc = __builtin_amdgcn_mfma_f32_16x16x32_bf16(pa, ones, lacc, 0, 0, 0);
        }
        __builtin_amdgcn_s_setprio(0);

        if (t + 1 < nt) store_kv(bs ^ 1);   // post-compute, pre-next-barrier
    };

    load_kv(0);
    store_kv(0);
    for (int t = 0; t < nt; t += 2) {       // unroll-2: bs literal
        tile_iter(t, 0);
        if (t + 1 < nt) tile_iter(t + 1, 1);
    }

    // ---- epilogue: O[q=4g+r][d=16n+a] / l (lacc already row-layout) ----
    float iv[4];
    #pragma unroll
    for (int r = 0; r < 4; ++r) iv[r] = 1.0f / lacc[r];
    float* Ob = O + ((size_t)b * LQ + qbase + wid * 16) * DH;
    #pragma unroll
    for (int n = 0; n < 4; ++n)
        #pragma unroll
        for (int r = 0; r < 4; ++r)
            Ob[(size_t)(4 * g + r) * DH + 16 * n + a] = oacc[n][r] * iv[r];
}

extern "C" void kernel_launch(void* const* d_in, const int* in_sizes, int n_in,
                              void* d_out, int out_size, void* d_ws, size_t ws_size,
                              hipStream_t stream) {
    const float* Q  = (const float*)d_in[0];
    const float* K  = (const float*)d_in[1];
    const float* V  = (const float*)d_in[2];
    const int*   VL = (const int*)d_in[3];
    float* O = (float*)d_out;

    attn_v21<<<NITEMS, 512, 0, stream>>>(Q, K, V, VL, O);
}